// Round 3
// baseline (513.420 us; speedup 1.0000x reference)
//
#include <hip/hip_runtime.h>
#include <hip/hip_bf16.h>

// Problem: B=64, L=8192, CIN=COUT=128, NCH=64
//   y[b,l,o] = tanh( sum_c x[b,l,c] * W[ch[l]][o][c] + bias[ch[l]][o] ) + x[b,l,o]
// I/O fp32; bf16 internally for MFMA (absmax 0.031, passes).
// HBM floor: x ~198 MB fetched (L3 helps) + y 274 MB written -> ~75 us @ 6.3 TB/s.
//
// This version vs round-1 (169 us, 2.85 TB/s, all pipes idle):
//  - LB=4 sites per block (grid 2048), double-buffered sA: next site's x is
//    prefetched to REGISTERS while the current site computes -> HBM pipe
//    stays fed through the compute/epilogue phases (T14 async-STAGE).
//  - W loads issued BEFORE x loads each iteration: vmcnt is in-order, so the
//    MFMA's wait on W never drains the slow HBM prefetch, and the staging
//    wait on x never drains the epilogue stores.
//  - __syncthreads() replaced by lgkmcnt(0)+s_barrier: stores and prefetch
//    loads stay in flight across the barrier (no vmcnt(0) drain). Only LDS
//    ordering is needed across the barrier (all cross-wave data is in sA).

#define BB   64
#define LL   8192
#define CIN  128
#define COUT 128
#define NCH  64
#define LB   4
#define PA   136  // sA padded row stride (bf16 elems)

typedef __bf16 bf16x4 __attribute__((ext_vector_type(4)));
typedef __bf16 bf16x8 __attribute__((ext_vector_type(8)));
typedef float  f32x4  __attribute__((ext_vector_type(4)));

// LDS-only barrier: waits ds ops, NOT vmem (stores/prefetch stay in flight).
#define LGKM_BARRIER()                                          \
    do {                                                        \
        asm volatile("s_waitcnt lgkmcnt(0)" ::: "memory");      \
        __builtin_amdgcn_s_barrier();                           \
    } while (0)

// channels is int64 in the reference; harness may stage as int32. Probe:
// for int64 (values 0..63) every odd 32-bit word is 0.
__global__ void convert_w_kernel(const float* __restrict__ w,
                                 __hip_bfloat16* __restrict__ wb)
{
    int i = (blockIdx.x * 256 + threadIdx.x) * 8;   // 512 x 256 x 8 = 1M elems
    float4 a = *(const float4*)(w + i);
    float4 b = *(const float4*)(w + i + 4);
    bf16x8 r = { (__bf16)a.x, (__bf16)a.y, (__bf16)a.z, (__bf16)a.w,
                 (__bf16)b.x, (__bf16)b.y, (__bf16)b.z, (__bf16)b.w };
    *(bf16x8*)(wb + i) = r;
}

template<bool PRE>
__global__ __launch_bounds__(256, 4) void gather_gemm_kernel(
    const float* __restrict__ x,
    const int* __restrict__ channels,
    const float* __restrict__ weight,
    const __hip_bfloat16* __restrict__ wbf,
    const float* __restrict__ bias,
    float* __restrict__ out)
{
    __shared__ __align__(16) __hip_bfloat16 sA[2][BB * PA];   // 2 x 17408 B

    const int l0 = blockIdx.x * LB;
    const int t  = threadIdx.x;

    bool is64 = true;
    #pragma unroll
    for (int i = 1; i < 32; i += 2) is64 = is64 && (channels[i] == 0);
    int chs[LB];
    #pragma unroll
    for (int j = 0; j < LB; ++j)
        chs[j] = is64 ? channels[2 * (l0 + j)] : channels[l0 + j];

    const int wave = t >> 6;   // 0..3 -> output rows o in [wave*32, wave*32+32)
    const int lane = t & 63;
    const int n0   = lane & 15;
    const int quad = lane >> 4;

    bf16x8 wfr[2][4];   // W fragments for current tile (32 VGPR)
    float4  xr[8];      // x prefetch for next tile (32 VGPR)

#define LOAD_W(ch_)                                                           \
    if constexpr (PRE) {                                                      \
        const __hip_bfloat16* wbc = wbf + (size_t)(ch_) * (COUT * CIN);       \
        _Pragma("unroll")                                                     \
        for (int oi = 0; oi < 2; ++oi) {                                      \
            int n = wave * 32 + oi * 16 + n0;                                 \
            _Pragma("unroll")                                                 \
            for (int ks = 0; ks < 4; ++ks)                                    \
                wfr[oi][ks] = *(const bf16x8*)(wbc + n * CIN + ks * 32 + quad * 8); \
        }                                                                     \
    } else {                                                                  \
        const float* wc = weight + (size_t)(ch_) * (COUT * CIN);              \
        _Pragma("unroll")                                                     \
        for (int oi = 0; oi < 2; ++oi) {                                      \
            int n = wave * 32 + oi * 16 + n0;                                 \
            _Pragma("unroll")                                                 \
            for (int ks = 0; ks < 4; ++ks) {                                  \
                const float* p = wc + n * CIN + ks * 32 + quad * 8;           \
                float4 a = *(const float4*)(p);                               \
                float4 b = *(const float4*)(p + 4);                           \
                wfr[oi][ks] = (bf16x8){(__bf16)a.x, (__bf16)a.y, (__bf16)a.z, (__bf16)a.w, \
                                       (__bf16)b.x, (__bf16)b.y, (__bf16)b.z, (__bf16)b.w}; \
            }                                                                 \
        }                                                                     \
    }

#define LOAD_X(lidx)                                                          \
    {                                                                         \
        const float* xl = x + (size_t)(lidx) * CIN;                           \
        _Pragma("unroll")                                                     \
        for (int i = 0; i < 8; ++i) {                                         \
            int c = t + 256 * i, row = c >> 5, cc = c & 31;                   \
            xr[i] = *(const float4*)(xl + (size_t)row * ((size_t)LL * CIN) + cc * 4); \
        }                                                                     \
    }

#define STAGE_X(buf)                                                          \
    {                                                                         \
        _Pragma("unroll")                                                     \
        for (int i = 0; i < 8; ++i) {                                         \
            int c = t + 256 * i, row = c >> 5, cc = c & 31;                   \
            bf16x4 b4 = {(__bf16)xr[i].x, (__bf16)xr[i].y,                    \
                         (__bf16)xr[i].z, (__bf16)xr[i].w};                   \
            *(bf16x4*)(&sA[buf][row * PA + cc * 4]) = b4;                     \
        }                                                                     \
    }

    // ---- Prologue: W(tile0) [L2] then x(tile0) [HBM], stage into buf 0 ----
    LOAD_W(chs[0]);
    LOAD_X(l0);
    STAGE_X(0);
    LGKM_BARRIER();

    #pragma unroll
    for (int j = 0; j < LB; ++j) {
        const int cur = j & 1;
        if (j > 0) { LOAD_W(chs[j]); }          // L2-resident, issued first
        if (j + 1 < LB) { LOAD_X(l0 + j + 1); } // HBM prefetch, issued second

        f32x4 acc[2][4];
        #pragma unroll
        for (int oi = 0; oi < 2; ++oi)
            #pragma unroll
            for (int bj = 0; bj < 4; ++bj)
                acc[oi][bj] = (f32x4){0.f, 0.f, 0.f, 0.f};

        // K=128 in 4 steps of 32.  mfma(W_frag, A_frag) -> D[o][b] (C^T)
        #pragma unroll
        for (int ks = 0; ks < 4; ++ks) {
            const int k = ks * 32 + quad * 8;
            bf16x8 afr[4];
            #pragma unroll
            for (int bj = 0; bj < 4; ++bj)
                afr[bj] = *(const bf16x8*)(&sA[cur][(bj * 16 + n0) * PA + k]);
            #pragma unroll
            for (int oi = 0; oi < 2; ++oi)
                #pragma unroll
                for (int bj = 0; bj < 4; ++bj)
                    acc[oi][bj] = __builtin_amdgcn_mfma_f32_16x16x32_bf16(
                        wfr[oi][ks], afr[bj], acc[oi][bj], 0, 0, 0);
        }

        // ---- Epilogue: +bias, tanh, +residual, float4 store ----
        // D layout (C^T): o = wave*32 + oi*16 + quad*4 + r ; b = bj*16 + n0
        const int l  = l0 + j;
        const int ch = chs[j];
        #pragma unroll
        for (int oi = 0; oi < 2; ++oi) {
            const int o0 = wave * 32 + oi * 16 + quad * 4;
            const f32x4 bv = *(const f32x4*)(bias + ch * COUT + o0);
            #pragma unroll
            for (int bj = 0; bj < 4; ++bj) {
                const int b = bj * 16 + n0;
                const bf16x4 rb = *(const bf16x4*)(&sA[cur][b * PA + o0]);
                f32x4 v;
                #pragma unroll
                for (int r = 0; r < 4; ++r) {
                    float vv = acc[oi][bj][r] + bv[r];
                    float e  = __expf(2.0f * vv);
                    float th = 1.0f - 2.0f * __builtin_amdgcn_rcpf(e + 1.0f);
                    v[r] = th + (float)rb[r];
                }
                *(f32x4*)(&out[((size_t)b * LL + l) * COUT + o0]) = v;
            }
        }

        // ---- Stage prefetched x into the other buffer, LDS-only barrier ----
        if (j + 1 < LB) {
            STAGE_X(cur ^ 1);
            LGKM_BARRIER();
        }
    }
#undef LOAD_W
#undef LOAD_X
#undef STAGE_X
}

__global__ void chan_out_kernel(const int* __restrict__ channels,
                                float* __restrict__ out)
{
    bool is64 = true;
    #pragma unroll
    for (int i = 1; i < 32; i += 2) is64 = is64 && (channels[i] == 0);
    int i = blockIdx.x * blockDim.x + threadIdx.x;
    int v = is64 ? channels[2 * i] : channels[i];
    if (i < LL)
        out[(size_t)BB * LL * COUT + i] = (float)v;
}

extern "C" void kernel_launch(void* const* d_in, const int* in_sizes, int n_in,
                              void* d_out, int out_size, void* d_ws, size_t ws_size,
                              hipStream_t stream) {
    const float* x        = (const float*)d_in[0];
    const int*   channels = (const int*)d_in[1];
    const float* weight   = (const float*)d_in[2];
    const float* bias     = (const float*)d_in[3];
    float*       out      = (float*)d_out;

    const size_t wbytes = (size_t)NCH * COUT * CIN * sizeof(__hip_bfloat16);  // 2 MB
    if (ws_size >= wbytes) {
        __hip_bfloat16* wbf = (__hip_bfloat16*)d_ws;
        convert_w_kernel<<<dim3(512), dim3(256), 0, stream>>>(weight, wbf);
        gather_gemm_kernel<true><<<dim3(LL / LB), dim3(256), 0, stream>>>(
            x, channels, weight, wbf, bias, out);
    } else {
        gather_gemm_kernel<false><<<dim3(LL / LB), dim3(256), 0, stream>>>(
            x, channels, weight, nullptr, bias, out);
    }
    chan_out_kernel<<<dim3(LL / 256), dim3(256), 0, stream>>>(channels, out);
}

// Round 5
// 508.944 us; speedup vs baseline: 1.0088x; 1.0088x over previous
//
#include <hip/hip_runtime.h>
#include <hip/hip_bf16.h>

// Problem: B=64, L=8192, CIN=COUT=128, NCH=64
//   y[b,l,o] = tanh( sum_c x[b,l,c] * W[ch[l]][o][c] + bias[ch[l]][o] ) + x[b,l,o]
// I/O fp32; bf16 internally for MFMA only. Residual is exact fp32 now.
// HBM floor: ~190 MB fetch (L3 holds most of x across iters) + 274 MB write
//   -> ~74 us @ 6.3 TB/s achievable.
//
// Round-3 failure: reg-prefetch of x was SUNK by the register allocator
// (VGPR=64 proved xr[] never lived across compute) -> serial stage/compute.
// This version uses global_load_lds (no VGPR dest => cannot be sunk), the
// 2-phase counted-vmcnt template:
//   iter j: load W+bias (L2) -> sched_barrier -> 8x glds for site j+1 (HBM)
//           -> sched_barrier -> kloop(ds_read fp32 + cvt + MFMA) -> epilogue
//           -> s_waitcnt vmcnt(8) (glds done, 8 stores stay in flight)
//           -> s_barrier
// Backend waits W with vmcnt(8) (W issued BEFORE glds; in-order retirement)
// so the HBM prefetch is never drained by compute.
// LDS layout: linear [64][128] f32 per buffer (glds requires linear dest);
// bank conflicts fixed by XOR swizzle g^=(row&7) at 16B granularity applied
// to the per-lane GLOBAL source address (m173 pattern) + matching read XOR.

#define BB   64
#define LL   8192
#define CIN  128
#define COUT 128
#define NCH  64
#define LB   16            // sites per block
#define GRID (LL / LB)     // 512 blocks = 2 per CU, all resident

typedef __bf16 bf16x8 __attribute__((ext_vector_type(8)));
typedef float  f32x4  __attribute__((ext_vector_type(4)));

typedef const __attribute__((address_space(1))) void gvoid_t;
typedef __attribute__((address_space(3))) void svoid_t;

__global__ void convert_w_kernel(const float* __restrict__ w,
                                 __hip_bfloat16* __restrict__ wb)
{
    int i = (blockIdx.x * 256 + threadIdx.x) * 8;   // 512 x 256 x 8 = 1M elems
    float4 a = *(const float4*)(w + i);
    float4 b = *(const float4*)(w + i + 4);
    bf16x8 r = { (__bf16)a.x, (__bf16)a.y, (__bf16)a.z, (__bf16)a.w,
                 (__bf16)b.x, (__bf16)b.y, (__bf16)b.z, (__bf16)b.w };
    *(bf16x8*)(wb + i) = r;
}

template<bool PRE>
__global__ __launch_bounds__(256, 2) void gather_gemm_kernel(
    const float* __restrict__ x,
    const int* __restrict__ channels,
    const float* __restrict__ weight,
    const __hip_bfloat16* __restrict__ wbf,
    const float* __restrict__ bias,
    float* __restrict__ out)
{
    __shared__ __align__(16) float sX[2][BB * CIN];   // 2 x 32 KB fp32

    const int l0   = blockIdx.x * LB;
    const int t    = threadIdx.x;
    const int wv   = t >> 6;
    const int ln   = t & 63;
    const int n0   = ln & 15;
    const int quad = ln >> 4;

    // channels is int64 in the reference; harness may stage as int32.
    // Probe: int64 values 0..63 => every odd 32-bit word is 0.
    bool is64 = true;
    #pragma unroll
    for (int i = 1; i < 32; i += 2) is64 = is64 && (channels[i] == 0);

    // Stage site lidx into sX[buf]: 2048 granules (16B), linear LDS dest,
    // XOR-swizzled global source (granule g of row r fetched from g^(r&7)).
#define STAGE(buf, lidx)                                                      \
    do {                                                                      \
        const float* xl_ = x + (size_t)(lidx) * CIN;                          \
        _Pragma("unroll")                                                     \
        for (int i_ = 0; i_ < 8; ++i_) {                                      \
            int D0 = i_ * 256 + wv * 64;     /* wave-uniform granule base */  \
            int d  = D0 + ln;                                                 \
            int r  = d >> 5;                 /* batch row   */                \
            int g  = d & 31;                 /* 16B granule */                \
            int gs = g ^ (r & 7);                                             \
            const float* src_ = xl_ + (size_t)r * ((size_t)LL * CIN) + gs * 4;\
            __builtin_amdgcn_global_load_lds((gvoid_t*)src_,                  \
                (svoid_t*)&sX[buf][D0 * 4], 16, 0, 0);                        \
        }                                                                     \
    } while (0)

    // ---- Prologue: stage site 0, full drain once ----
    int ch_cur = is64 ? channels[2 * l0] : channels[l0];
    STAGE(0, l0);
    asm volatile("s_waitcnt vmcnt(0)" ::: "memory");
    __builtin_amdgcn_s_barrier();

    #pragma unroll 2
    for (int j = 0; j < LB; ++j) {
        const int cur = j & 1;
        const float* sXc = sX[cur];
        const int lnext = l0 + j + 1;
        int ch_nxt = 0;
        if (j + 1 < LB)
            ch_nxt = is64 ? channels[2 * lnext] : channels[lnext];

        // ---- W + bias for current site (L2-resident), BEFORE glds ----
        bf16x8 wfr[2][4];
        f32x4  bv[2];
        if constexpr (PRE) {
            const __hip_bfloat16* wbc = wbf + (size_t)ch_cur * (COUT * CIN);
            #pragma unroll
            for (int oi = 0; oi < 2; ++oi) {
                const int n = wv * 32 + oi * 16 + n0;
                #pragma unroll
                for (int ks = 0; ks < 4; ++ks)
                    wfr[oi][ks] = *(const bf16x8*)(wbc + n * CIN + ks * 32 + quad * 8);
                bv[oi] = *(const f32x4*)(bias + ch_cur * COUT + wv * 32 + oi * 16 + quad * 4);
            }
        } else {
            const float* wc = weight + (size_t)ch_cur * (COUT * CIN);
            #pragma unroll
            for (int oi = 0; oi < 2; ++oi) {
                const int n = wv * 32 + oi * 16 + n0;
                #pragma unroll
                for (int ks = 0; ks < 4; ++ks) {
                    const float* p = wc + n * CIN + ks * 32 + quad * 8;
                    float4 a = *(const float4*)(p);
                    float4 b = *(const float4*)(p + 4);
                    wfr[oi][ks] = (bf16x8){(__bf16)a.x, (__bf16)a.y, (__bf16)a.z, (__bf16)a.w,
                                           (__bf16)b.x, (__bf16)b.y, (__bf16)b.z, (__bf16)b.w};
                }
                bv[oi] = *(const f32x4*)(bias + ch_cur * COUT + wv * 32 + oi * 16 + quad * 4);
            }
        }
        __builtin_amdgcn_sched_barrier(0);   // keep W/bias issued before glds
        if (j + 1 < LB) STAGE(cur ^ 1, lnext);
        __builtin_amdgcn_sched_barrier(0);   // keep glds issued before compute

        // ---- K-loop: fp32 frags from LDS (swizzled), cvt->bf16, MFMA ----
        f32x4 acc[2][4];
        #pragma unroll
        for (int oi = 0; oi < 2; ++oi)
            #pragma unroll
            for (int bj = 0; bj < 4; ++bj)
                acc[oi][bj] = (f32x4){0.f, 0.f, 0.f, 0.f};

        #pragma unroll
        for (int ks = 0; ks < 4; ++ks) {
            bf16x8 afr[4];
            #pragma unroll
            for (int bj = 0; bj < 4; ++bj) {
                const int m  = bj * 16 + n0;
                const int s  = m & 7;
                const int g0 = ks * 8 + quad * 2;
                f32x4 a0 = *(const f32x4*)&sXc[m * CIN + ((g0    ) ^ s) * 4];
                f32x4 a1 = *(const f32x4*)&sXc[m * CIN + ((g0 + 1) ^ s) * 4];
                afr[bj] = (bf16x8){(__bf16)a0.x, (__bf16)a0.y, (__bf16)a0.z, (__bf16)a0.w,
                                   (__bf16)a1.x, (__bf16)a1.y, (__bf16)a1.z, (__bf16)a1.w};
            }
            #pragma unroll
            for (int oi = 0; oi < 2; ++oi)
                #pragma unroll
                for (int bj = 0; bj < 4; ++bj)
                    acc[oi][bj] = __builtin_amdgcn_mfma_f32_16x16x32_bf16(
                        wfr[oi][ks], afr[bj], acc[oi][bj], 0, 0, 0);
        }

        // ---- Epilogue: +bias, tanh, +fp32 residual (swizzled LDS), store ----
        // D layout (C^T): o = wv*32 + oi*16 + quad*4 + r ; b = bj*16 + n0
        const int l = l0 + j;
        #pragma unroll
        for (int oi = 0; oi < 2; ++oi) {
            const int o0 = wv * 32 + oi * 16 + quad * 4;
            const int gr = o0 >> 2;
            #pragma unroll
            for (int bj = 0; bj < 4; ++bj) {
                const int b = bj * 16 + n0;
                f32x4 res = *(const f32x4*)&sXc[b * CIN + (gr ^ (b & 7)) * 4];
                f32x4 v;
                #pragma unroll
                for (int r = 0; r < 4; ++r) {
                    float vv = acc[oi][bj][r] + bv[oi][r];
                    float e  = __expf(2.0f * vv);
                    float th = 1.0f - 2.0f * __builtin_amdgcn_rcpf(e + 1.0f);
                    v[r] = th + res[r];
                }
                *(f32x4*)(&out[((size_t)b * LL + l) * COUT + o0]) = v;
            }
        }

        // ---- Counted drain: glds(j+1)+W done; 8 stores stay in flight ----
        if (j + 1 < LB) {
            asm volatile("s_waitcnt vmcnt(8)" ::: "memory");
            __builtin_amdgcn_s_barrier();
        }
        ch_cur = ch_nxt;
    }
#undef STAGE
}

__global__ void chan_out_kernel(const int* __restrict__ channels,
                                float* __restrict__ out)
{
    bool is64 = true;
    #pragma unroll
    for (int i = 1; i < 32; i += 2) is64 = is64 && (channels[i] == 0);
    int i = blockIdx.x * blockDim.x + threadIdx.x;
    int v = is64 ? channels[2 * i] : channels[i];
    if (i < LL)
        out[(size_t)BB * LL * COUT + i] = (float)v;
}

extern "C" void kernel_launch(void* const* d_in, const int* in_sizes, int n_in,
                              void* d_out, int out_size, void* d_ws, size_t ws_size,
                              hipStream_t stream) {
    const float* x        = (const float*)d_in[0];
    const int*   channels = (const int*)d_in[1];
    const float* weight   = (const float*)d_in[2];
    const float* bias     = (const float*)d_in[3];
    float*       out      = (float*)d_out;

    const size_t wbytes = (size_t)NCH * COUT * CIN * sizeof(__hip_bfloat16);  // 2 MB
    if (ws_size >= wbytes) {
        __hip_bfloat16* wbf = (__hip_bfloat16*)d_ws;
        convert_w_kernel<<<dim3(512), dim3(256), 0, stream>>>(weight, wbf);
        gather_gemm_kernel<true><<<dim3(GRID), dim3(256), 0, stream>>>(
            x, channels, weight, wbf, bias, out);
    } else {
        gather_gemm_kernel<false><<<dim3(GRID), dim3(256), 0, stream>>>(
            x, channels, weight, nullptr, bias, out);
    }
    chan_out_kernel<<<dim3(LL / 256), dim3(256), 0, stream>>>(channels, out);
}